// Round 1
// baseline (354.661 us; speedup 1.0000x reference)
//
#include <hip/hip_runtime.h>
#include <hip/hip_bf16.h>
#include <stdint.h>

// RecursiveDecoder: M=128 children, H=F=256, T=4 edge types, 2 MP iters, NSEM=57.
// Key algebraic decompositions:
//   EL[i,j,:]   = relu(A[i,:] + B[j,:] + b_el),  A = cf@W_el[0:256], B = cf@W_el[256:512]
//   msg[e,:]    = relu(P[i,:] + Q[j,:] + R[p,:] + logit_e * W4[t,:]),  p = i*128+j
//     P = cf_it@W1 + b_ne, Q = cf_it@W2, R = EL@W3  (the only big GEMM: [16384,256]@[256,256])
// Mask-critical values (exists logits, edge logits) computed in fp32; only EL->R in bf16 MFMA.
// ws layout (bytes): cf0 0 | cf1 128K | cf2 256K | A 384K | B 512K | P 640K | Q 768K |
//   ex0 896K | W3T(bf16 x2, swizzled) 1M | ELbf(bf16, swizzled) 2M..10M | R 12M..28M
// Requires ws_size >= 29360128.

typedef unsigned short ushort_t;
using f32x4 = __attribute__((ext_vector_type(4))) float;
using s16x8 = __attribute__((ext_vector_type(8))) short;

__device__ __forceinline__ ushort_t f2bf(float x) {
  __hip_bfloat16 h = __float2bfloat16(x);
  return *reinterpret_cast<ushort_t*>(&h);
}

// ---------- K1: child_feats = relu(pf @ W_parent + b_parent), pf = [pf|code16|code10] ----------
__global__ __launch_bounds__(256) void k1_parent(
    const float* __restrict__ p0, const float* __restrict__ p1, const float* __restrict__ p2,
    const float* __restrict__ W, const float* __restrict__ b, float* __restrict__ cf) {
  __shared__ float pfs[282];
  __shared__ float red[128];
  int tid = threadIdx.x;
  pfs[tid] = (tid < 256) ? p0[tid] : 0.f;
  if (tid < 16) pfs[256 + tid] = p1[tid];
  if (tid < 10) pfs[272 + tid] = p2[tid];
  __syncthreads();
  int col = blockIdx.x * 128 + (tid & 127);
  int kh = tid >> 7;          // k-half: 0 -> [0,141), 1 -> [141,282)
  int k0 = kh * 141;
  float acc = 0.f;
  #pragma unroll 4
  for (int k = 0; k < 141; ++k)
    acc += pfs[k0 + k] * W[(size_t)(k0 + k) * 32768 + col];
  if (kh) red[tid & 127] = acc;
  __syncthreads();
  if (!kh) {
    float v = acc + red[tid] + b[col];
    cf[col] = v > 0.f ? v : 0.f;
  }
}

// ---------- K2: A,B = cf @ W_el halves (fp32); exists logits (fp32, mask-critical) ----------
__global__ __launch_bounds__(256) void k2_ab(
    const float* __restrict__ cf, const float* __restrict__ Wel,
    const float* __restrict__ Wex, const float* __restrict__ bex,
    float* __restrict__ A, float* __restrict__ B, float* __restrict__ ex0,
    float* __restrict__ exout) {
  __shared__ float c[256];
  __shared__ float wsum[4];
  int tid = threadIdx.x, r = blockIdx.x;
  c[tid] = cf[r * 256 + tid];
  __syncthreads();
  float accA = 0.f, accB = 0.f;
  #pragma unroll 4
  for (int k = 0; k < 256; ++k) {
    float cv = c[k];
    accA += cv * Wel[k * 256 + tid];
    accB += cv * Wel[(256 + k) * 256 + tid];
  }
  A[r * 256 + tid] = accA;
  B[r * 256 + tid] = accB;
  float v = c[tid] * Wex[tid];
  #pragma unroll
  for (int off = 32; off; off >>= 1) v += __shfl_xor(v, off);
  if ((tid & 63) == 0) wsum[tid >> 6] = v;
  __syncthreads();
  if (tid == 0) {
    float lg = wsum[0] + wsum[1] + wsum[2] + wsum[3] + bex[0];
    exout[r] = lg;
    ex0[r] = lg > 0.f ? 1.f : 0.f;
  }
}

// ---------- K2b: pack W3 = W_ne[it][512:768] as bf16, transposed [n][k], XOR-swizzled ----------
__global__ __launch_bounds__(256) void k2b_pack(const float* __restrict__ Wne, ushort_t* __restrict__ W3T) {
  int idx = blockIdx.x * 256 + threadIdx.x;   // 2*65536 elements
  int it = idx >> 16;
  int rem = idx & 65535;
  int n = rem >> 8;            // constant per block
  int k = rem & 255;
  float v = Wne[(size_t)(it * 772 + 512 + k) * 256 + n];
  W3T[it * 65536 + n * 256 + (k ^ ((n & 7) << 3))] = f2bf(v);
}

// ---------- K3: EL = relu(A[i]+B[j]+b) -> bf16 swizzled; edge logits (fp32 einsum) ----------
__global__ __launch_bounds__(256) void k3_edge(
    const float* __restrict__ A, const float* __restrict__ B, const float* __restrict__ bel,
    const float* __restrict__ Wee, const float* __restrict__ bee,
    ushort_t* __restrict__ ELbf, float* __restrict__ elog) {
  __shared__ float wsum[4][4];
  int tid = threadIdx.x;
  int p = blockIdx.x;                 // pair index i*128+j
  int i = p >> 7, j = p & 127;
  float el = A[i * 256 + tid] + B[j * 256 + tid] + bel[tid];
  el = el > 0.f ? el : 0.f;
  ELbf[(size_t)p * 256 + (tid ^ ((p & 7) << 3))] = f2bf(el);
  float pt0 = el * Wee[tid], pt1 = el * Wee[256 + tid];
  float pt2 = el * Wee[512 + tid], pt3 = el * Wee[768 + tid];
  #pragma unroll
  for (int off = 32; off; off >>= 1) {
    pt0 += __shfl_xor(pt0, off);
    pt1 += __shfl_xor(pt1, off);
    pt2 += __shfl_xor(pt2, off);
    pt3 += __shfl_xor(pt3, off);
  }
  int wid = tid >> 6;
  if ((tid & 63) == 0) { wsum[wid][0] = pt0; wsum[wid][1] = pt1; wsum[wid][2] = pt2; wsum[wid][3] = pt3; }
  __syncthreads();
  if (tid < 4)
    elog[p * 4 + tid] = wsum[0][tid] + wsum[1][tid] + wsum[2][tid] + wsum[3][tid] + bee[tid];
}

// ---------- K4a: R = ELbf[16384,256] @ W3[256,256]  (bf16 MFMA, fp32 out) ----------
// Both operands stored pre-swizzled (k ^= (row&7)<<3 within 64-k tiles) so global_load_lds
// stays linear and ds_read_b128 is bank-conflict-free (guide G4/rule 21).
__global__ __launch_bounds__(256) void k_gemm(
    const ushort_t* __restrict__ Abuf, const ushort_t* __restrict__ Bbuf, float* __restrict__ C) {
  __shared__ __align__(16) ushort_t lA[128 * 64];
  __shared__ __align__(16) ushort_t lB[128 * 64];
  int tid = threadIdx.x;
  int lane = tid & 63, wid = tid >> 6;
  int bp = blockIdx.x, bn = blockIdx.y;
  int wr = wid >> 1, wc = wid & 1;      // wave quadrant (64x64)
  f32x4 acc[4][4] = {};
  for (int ks = 0; ks < 256; ks += 64) {
    __syncthreads();
    #pragma unroll
    for (int rr = 0; rr < 4; ++rr) {
      int c = rr * 4 + wid;             // 1KB chunk 0..15 (wave-uniform)
      int row = c * 8 + (lane >> 3);    // tile row 0..127
      int co = (lane & 7) * 8;          // ushort offset in 64-wide row
      const ushort_t* sa = Abuf + (size_t)(bp * 128 + row) * 256 + ks + co;
      const ushort_t* sb = Bbuf + (size_t)(bn * 128 + row) * 256 + ks + co;
      __builtin_amdgcn_global_load_lds((const __attribute__((address_space(1))) void*)sa,
                                       (__attribute__((address_space(3))) void*)(lA + c * 512), 16, 0, 0);
      __builtin_amdgcn_global_load_lds((const __attribute__((address_space(1))) void*)sb,
                                       (__attribute__((address_space(3))) void*)(lB + c * 512), 16, 0, 0);
    }
    __syncthreads();   // compiler drains vmcnt before barrier
    #pragma unroll
    for (int kk = 0; kk < 2; ++kk) {
      s16x8 af[4], bfr[4];
      #pragma unroll
      for (int mt = 0; mt < 4; ++mt) {
        int row = wr * 64 + mt * 16 + (lane & 15);
        int kl = kk * 32 + (lane >> 4) * 8;
        int kls = kl ^ ((row & 7) << 3);
        af[mt] = *reinterpret_cast<const s16x8*>(&lA[row * 64 + kls]);
      }
      #pragma unroll
      for (int nt = 0; nt < 4; ++nt) {
        int row = wc * 64 + nt * 16 + (lane & 15);
        int kl = kk * 32 + (lane >> 4) * 8;
        int kls = kl ^ ((row & 7) << 3);
        bfr[nt] = *reinterpret_cast<const s16x8*>(&lB[row * 64 + kls]);
      }
      #pragma unroll
      for (int mt = 0; mt < 4; ++mt)
        #pragma unroll
        for (int nt = 0; nt < 4; ++nt)
          acc[mt][nt] = __builtin_amdgcn_mfma_f32_16x16x32_bf16(af[mt], bfr[nt], acc[mt][nt], 0, 0, 0);
    }
  }
  int colbase = bn * 128 + wc * 64 + (lane & 15);
  int rowbase = bp * 128 + wr * 64 + (lane >> 4) * 4;
  #pragma unroll
  for (int mt = 0; mt < 4; ++mt)
    #pragma unroll
    for (int nt = 0; nt < 4; ++nt)
      #pragma unroll
      for (int r = 0; r < 4; ++r)
        C[(size_t)(rowbase + mt * 16 + r) * 256 + colbase + nt * 16] = acc[mt][nt][r];
}

// ---------- KP: P = cf_it@W1 + b_ne, Q = cf_it@W2 ----------
__global__ __launch_bounds__(256) void kp(
    const float* __restrict__ cf, const float* __restrict__ Wne_it, const float* __restrict__ bne_it,
    float* __restrict__ P, float* __restrict__ Q) {
  __shared__ float c[256];
  int tid = threadIdx.x, r = blockIdx.x;
  c[tid] = cf[r * 256 + tid];
  __syncthreads();
  float accP = bne_it[tid], accQ = 0.f;
  #pragma unroll 4
  for (int k = 0; k < 256; ++k) {
    float cv = c[k];
    accP += cv * Wne_it[k * 256 + tid];
    accQ += cv * Wne_it[(256 + k) * 256 + tid];
  }
  P[r * 256 + tid] = accP;
  Q[r * 256 + tid] = accQ;
}

// ---------- K4b: cf_next[i] = max(0, max_{j,t masked}(P[i]+Q[j]+R[i*128+j]+lg*W4[t])) ----------
__global__ __launch_bounds__(256) void k4b_scatter(
    const float* __restrict__ P, const float* __restrict__ Q, const float* __restrict__ R,
    const float* __restrict__ elog, const float* __restrict__ ex0,
    const float* __restrict__ Wne_it, float* __restrict__ cfn) {
  __shared__ float sl[128 * 4];
  __shared__ float se[128];
  int tid = threadIdx.x, i = blockIdx.x;
  if (ex0[i] == 0.f) { cfn[i * 256 + tid] = 0.f; return; }   // block-uniform branch
  for (int idx = tid; idx < 512; idx += 256) sl[idx] = elog[i * 512 + idx];
  if (tid < 128) se[tid] = ex0[tid];
  __syncthreads();
  float p = P[i * 256 + tid];
  float w40 = Wne_it[768 * 256 + tid];
  float w41 = Wne_it[769 * 256 + tid];
  float w42 = Wne_it[770 * 256 + tid];
  float w43 = Wne_it[771 * 256 + tid];
  float acc = 0.f;                                            // zero-init == relu + empty case
  for (int j = 0; j < 128; ++j) {
    if (se[j] == 0.f) continue;                               // block-uniform
    float base = p + Q[j * 256 + tid] + R[(size_t)(i * 128 + j) * 256 + tid];
    float l0 = sl[j * 4 + 0], l1 = sl[j * 4 + 1], l2 = sl[j * 4 + 2], l3 = sl[j * 4 + 3];
    if (l0 > 0.f) { float m = base + l0 * w40; acc = acc > m ? acc : m; }
    if (l1 > 0.f) { float m = base + l1 * w41; acc = acc > m ? acc : m; }
    if (l2 > 0.f) { float m = base + l2 * w42; acc = acc > m ? acc : m; }
    if (l3 > 0.f) { float m = base + l3 * w43; acc = acc > m ? acc : m; }
  }
  cfn[i * 256 + tid] = acc;
}

// ---------- K6: h = relu([cf0|cf1|cf2]@W_child+b); sem = h@W_sem+b; out = relu(h@W_child2+b) ----------
__global__ __launch_bounds__(256) void k6_final(
    const float* __restrict__ cf0, const float* __restrict__ cf1, const float* __restrict__ cf2,
    const float* __restrict__ Wc, const float* __restrict__ bc,
    const float* __restrict__ Wsem, const float* __restrict__ bsem,
    const float* __restrict__ W2, const float* __restrict__ b2,
    float* __restrict__ out) {
  __shared__ float af[768];
  __shared__ float hb[256];
  int tid = threadIdx.x, m = blockIdx.x;
  af[tid] = cf0[m * 256 + tid];
  af[256 + tid] = cf1[m * 256 + tid];
  af[512 + tid] = cf2[m * 256 + tid];
  __syncthreads();
  float acc = bc[tid];
  #pragma unroll 4
  for (int k = 0; k < 768; ++k) acc += af[k] * Wc[k * 256 + tid];
  float hv = acc > 0.f ? acc : 0.f;
  hb[tid] = hv;
  __syncthreads();
  float acc2 = b2[tid];
  #pragma unroll 4
  for (int k = 0; k < 256; ++k) acc2 += hb[k] * W2[k * 256 + tid];
  out[m * 256 + tid] = acc2 > 0.f ? acc2 : 0.f;
  if (tid < 57) {
    float accs = bsem[tid];
    for (int k = 0; k < 256; ++k) accs += hb[k] * Wsem[k * 57 + tid];
    out[32768 + m * 57 + tid] = accs;
  }
}

extern "C" void kernel_launch(void* const* d_in, const int* in_sizes, int n_in,
                              void* d_out, int out_size, void* d_ws, size_t ws_size,
                              hipStream_t stream) {
  const float* p0  = (const float*)d_in[0];
  const float* p1  = (const float*)d_in[1];
  const float* p2  = (const float*)d_in[2];
  const float* Wp  = (const float*)d_in[3];
  const float* bp  = (const float*)d_in[4];
  const float* Wex = (const float*)d_in[5];
  const float* bex = (const float*)d_in[6];
  const float* Wsm = (const float*)d_in[7];
  const float* bsm = (const float*)d_in[8];
  const float* Wel = (const float*)d_in[9];
  const float* bel = (const float*)d_in[10];
  const float* Wee = (const float*)d_in[11];
  const float* bee = (const float*)d_in[12];
  const float* Wne = (const float*)d_in[13];
  const float* bne = (const float*)d_in[14];
  const float* Wc  = (const float*)d_in[15];
  const float* bc  = (const float*)d_in[16];
  const float* W2  = (const float*)d_in[17];
  const float* b2  = (const float*)d_in[18];
  float* out = (float*)d_out;

  char* ws = (char*)d_ws;
  float*    cf0  = (float*)(ws + 0);
  float*    cf1  = (float*)(ws + 131072);
  float*    cf2  = (float*)(ws + 262144);
  float*    Ab   = (float*)(ws + 393216);
  float*    Bb   = (float*)(ws + 524288);
  float*    Pb   = (float*)(ws + 655360);
  float*    Qb   = (float*)(ws + 786432);
  float*    ex0  = (float*)(ws + 917504);
  ushort_t* W3T  = (ushort_t*)(ws + 1048576);
  ushort_t* ELbf = (ushort_t*)(ws + 2097152);
  float*    R    = (float*)(ws + 12582912);

  float* out_co  = out;             // [128,256]
  float* out_sem = out + 32768;     // [128,57]
  float* out_ex  = out + 40064;     // [128]
  float* out_el  = out + 40192;     // [128,128,4]

  k1_parent<<<256, 256, 0, stream>>>(p0, p1, p2, Wp, bp, cf0);
  k2_ab<<<128, 256, 0, stream>>>(cf0, Wel, Wex, bex, Ab, Bb, ex0, out_ex);
  k2b_pack<<<512, 256, 0, stream>>>(Wne, W3T);
  k3_edge<<<16384, 256, 0, stream>>>(Ab, Bb, bel, Wee, bee, ELbf, out_el);
  for (int it = 0; it < 2; ++it) {
    const float* Wne_it = Wne + (size_t)it * 772 * 256;
    const float* cfi = it ? cf1 : cf0;
    float* cfn = it ? cf2 : cf1;
    k_gemm<<<dim3(128, 2), 256, 0, stream>>>(ELbf, W3T + it * 65536, R);
    kp<<<128, 256, 0, stream>>>(cfi, Wne_it, bne + it * 256, Pb, Qb);
    k4b_scatter<<<128, 256, 0, stream>>>(Pb, Qb, R, out_el, ex0, Wne_it, cfn);
  }
  k6_final<<<128, 256, 0, stream>>>(cf0, cf1, cf2, Wc, bc, Wsm, bsm, W2, b2, out);
}

// Round 2
// 194.778 us; speedup vs baseline: 1.8209x; 1.8209x over previous
//
#include <hip/hip_runtime.h>
#include <hip/hip_bf16.h>
#include <stdint.h>

// RecursiveDecoder: M=128 children, H=F=256, T=4 edge types, 2 MP iters, NSEM=57.
// Decompositions:
//   EL[i,j,:] = relu(A[i,:] + B[j,:] + b_el),  A = cf@W_el[0:256], B = cf@W_el[256:512]
//   msg[e,:]  = relu(P[i,:] + Q[j,:] + R[p,:] + logit_e * W4[t,:]),  p = i*128+j
//     P = cf_it@W1 + b_ne, Q = cf_it@W2, R = EL@W3 (only big GEMM, bf16 MFMA)
// Mask-critical values (exists/edge logits) stay fp32.
// R1 change: all small matvec kernels restructured from (128 blocks x 256 thr,
// serial k-loop) -> (256 blocks x 1024 thr, k split over 8 slices + LDS reduce).
// ws layout: cf0 0 | cf1 128K | cf2 256K | A 384K | B 512K | P 640K | Q 768K |
//   h 896K | ex0 1M | W3T 1.125M | ELbf 2M | R 12M  (needs ws >= 28M)

typedef unsigned short ushort_t;
using f32x4 = __attribute__((ext_vector_type(4))) float;
using s16x8 = __attribute__((ext_vector_type(8))) short;

__device__ __forceinline__ ushort_t f2bf(float x) {
  __hip_bfloat16 h = __float2bfloat16(x);
  return *reinterpret_cast<ushort_t*>(&h);
}

// ---------- K1: child_feats = relu(pf @ W_parent + b), 512 blocks x (64 cols, 4 k-slices) ----------
__global__ __launch_bounds__(256) void k1_parent(
    const float* __restrict__ p0, const float* __restrict__ p1, const float* __restrict__ p2,
    const float* __restrict__ W, const float* __restrict__ b, float* __restrict__ cf) {
  __shared__ float pfs[282];
  __shared__ float red[256];
  int tid = threadIdx.x;
  if (tid < 256) pfs[tid] = p0[tid];
  if (tid < 16) pfs[256 + tid] = p1[tid];
  if (tid < 10) pfs[272 + tid] = p2[tid];
  __syncthreads();
  int c = tid & 63, s = tid >> 6;
  int col = blockIdx.x * 64 + c;
  int k0 = (s * 282) >> 2, k1 = ((s + 1) * 282) >> 2;
  float acc = 0.f;
  #pragma unroll 8
  for (int k = k0; k < k1; ++k)
    acc += pfs[k] * W[(size_t)k * 32768 + col];
  red[tid] = acc;
  __syncthreads();
  if (tid < 64) {
    float v = red[tid] + red[64 + tid] + red[128 + tid] + red[192 + tid] + b[col];
    cf[col] = v > 0.f ? v : 0.f;
  }
}

// ---------- K2: A,B = cf @ W_el halves; exists logits. 256 blocks x 1024 thr ----------
__global__ __launch_bounds__(1024) void k2_ab(
    const float* __restrict__ cf, const float* __restrict__ Wel,
    const float* __restrict__ Wex, const float* __restrict__ bex,
    float* __restrict__ A, float* __restrict__ B, float* __restrict__ ex0,
    float* __restrict__ exout) {
  __shared__ float c[256];
  __shared__ float redA[1024];
  __shared__ float redB[1024];
  __shared__ float wsum[4];
  int tid = threadIdx.x;
  int r = blockIdx.x >> 1, half = blockIdx.x & 1;
  if (tid < 256) c[tid] = cf[r * 256 + tid];
  __syncthreads();
  int cc = tid & 127, s = tid >> 7;        // 8 k-slices of 32
  int col = half * 128 + cc;
  int k0 = s * 32;
  float accA = 0.f, accB = 0.f;
  #pragma unroll 8
  for (int kk = 0; kk < 32; ++kk) {
    float cv = c[k0 + kk];
    accA += cv * Wel[(k0 + kk) * 256 + col];
    accB += cv * Wel[(256 + k0 + kk) * 256 + col];
  }
  redA[tid] = accA;
  redB[tid] = accB;
  float v = 0.f;
  if (half == 0 && tid < 256) v = c[tid] * Wex[tid];
  #pragma unroll
  for (int off = 32; off; off >>= 1) v += __shfl_xor(v, off);
  if (half == 0 && tid < 256 && (tid & 63) == 0) wsum[tid >> 6] = v;
  __syncthreads();
  if (tid < 128) {
    float a = 0.f, bb = 0.f;
    #pragma unroll
    for (int q = 0; q < 8; ++q) { a += redA[q * 128 + tid]; bb += redB[q * 128 + tid]; }
    A[r * 256 + half * 128 + tid] = a;
    B[r * 256 + half * 128 + tid] = bb;
  }
  if (half == 0 && tid == 0) {
    float lg = wsum[0] + wsum[1] + wsum[2] + wsum[3] + bex[0];
    exout[r] = lg;
    ex0[r] = lg > 0.f ? 1.f : 0.f;
  }
}

// ---------- K2b: pack W3 = W_ne[it][512:768] as bf16 transposed [n][k], XOR-swizzled ----------
__global__ __launch_bounds__(256) void k2b_pack(const float* __restrict__ Wne, ushort_t* __restrict__ W3T) {
  int idx = blockIdx.x * 256 + threadIdx.x;   // 2*65536 elements
  int it = idx >> 16;
  int rem = idx & 65535;
  int n = rem >> 8;
  int k = rem & 255;
  float v = Wne[(size_t)(it * 772 + 512 + k) * 256 + n];
  W3T[it * 65536 + n * 256 + (k ^ ((n & 7) << 3))] = f2bf(v);
}

// ---------- K3: EL = relu(A[i]+B[j]+b) -> bf16 swizzled; edge logits (fp32) ----------
__global__ __launch_bounds__(256) void k3_edge(
    const float* __restrict__ A, const float* __restrict__ B, const float* __restrict__ bel,
    const float* __restrict__ Wee, const float* __restrict__ bee,
    ushort_t* __restrict__ ELbf, float* __restrict__ elog) {
  __shared__ float wsum[4][4];
  int tid = threadIdx.x;
  int p = blockIdx.x;                 // pair index i*128+j
  int i = p >> 7, j = p & 127;
  float el = A[i * 256 + tid] + B[j * 256 + tid] + bel[tid];
  el = el > 0.f ? el : 0.f;
  ELbf[(size_t)p * 256 + (tid ^ ((p & 7) << 3))] = f2bf(el);
  float pt0 = el * Wee[tid], pt1 = el * Wee[256 + tid];
  float pt2 = el * Wee[512 + tid], pt3 = el * Wee[768 + tid];
  #pragma unroll
  for (int off = 32; off; off >>= 1) {
    pt0 += __shfl_xor(pt0, off);
    pt1 += __shfl_xor(pt1, off);
    pt2 += __shfl_xor(pt2, off);
    pt3 += __shfl_xor(pt3, off);
  }
  int wid = tid >> 6;
  if ((tid & 63) == 0) { wsum[wid][0] = pt0; wsum[wid][1] = pt1; wsum[wid][2] = pt2; wsum[wid][3] = pt3; }
  __syncthreads();
  if (tid < 4)
    elog[p * 4 + tid] = wsum[0][tid] + wsum[1][tid] + wsum[2][tid] + wsum[3][tid] + bee[tid];
}

// ---------- K4a: R = ELbf[16384,256] @ W3[256,256]  (bf16 MFMA, fp32 out) ----------
__global__ __launch_bounds__(256) void k_gemm(
    const ushort_t* __restrict__ Abuf, const ushort_t* __restrict__ Bbuf, float* __restrict__ C) {
  __shared__ __align__(16) ushort_t lA[128 * 64];
  __shared__ __align__(16) ushort_t lB[128 * 64];
  int tid = threadIdx.x;
  int lane = tid & 63, wid = tid >> 6;
  int bp = blockIdx.x, bn = blockIdx.y;
  int wr = wid >> 1, wc = wid & 1;      // wave quadrant (64x64)
  f32x4 acc[4][4] = {};
  for (int ks = 0; ks < 256; ks += 64) {
    __syncthreads();
    #pragma unroll
    for (int rr = 0; rr < 4; ++rr) {
      int c = rr * 4 + wid;             // 1KB chunk 0..15 (wave-uniform)
      int row = c * 8 + (lane >> 3);    // tile row 0..127
      int co = (lane & 7) * 8;          // ushort offset in 64-wide row
      const ushort_t* sa = Abuf + (size_t)(bp * 128 + row) * 256 + ks + co;
      const ushort_t* sb = Bbuf + (size_t)(bn * 128 + row) * 256 + ks + co;
      __builtin_amdgcn_global_load_lds((const __attribute__((address_space(1))) void*)sa,
                                       (__attribute__((address_space(3))) void*)(lA + c * 512), 16, 0, 0);
      __builtin_amdgcn_global_load_lds((const __attribute__((address_space(1))) void*)sb,
                                       (__attribute__((address_space(3))) void*)(lB + c * 512), 16, 0, 0);
    }
    __syncthreads();
    #pragma unroll
    for (int kk = 0; kk < 2; ++kk) {
      s16x8 af[4], bfr[4];
      #pragma unroll
      for (int mt = 0; mt < 4; ++mt) {
        int row = wr * 64 + mt * 16 + (lane & 15);
        int kl = kk * 32 + (lane >> 4) * 8;
        int kls = kl ^ ((row & 7) << 3);
        af[mt] = *reinterpret_cast<const s16x8*>(&lA[row * 64 + kls]);
      }
      #pragma unroll
      for (int nt = 0; nt < 4; ++nt) {
        int row = wc * 64 + nt * 16 + (lane & 15);
        int kl = kk * 32 + (lane >> 4) * 8;
        int kls = kl ^ ((row & 7) << 3);
        bfr[nt] = *reinterpret_cast<const s16x8*>(&lB[row * 64 + kls]);
      }
      #pragma unroll
      for (int mt = 0; mt < 4; ++mt)
        #pragma unroll
        for (int nt = 0; nt < 4; ++nt)
          acc[mt][nt] = __builtin_amdgcn_mfma_f32_16x16x32_bf16(af[mt], bfr[nt], acc[mt][nt], 0, 0, 0);
    }
  }
  int colbase = bn * 128 + wc * 64 + (lane & 15);
  int rowbase = bp * 128 + wr * 64 + (lane >> 4) * 4;
  #pragma unroll
  for (int mt = 0; mt < 4; ++mt)
    #pragma unroll
    for (int nt = 0; nt < 4; ++nt)
      #pragma unroll
      for (int r = 0; r < 4; ++r)
        C[(size_t)(rowbase + mt * 16 + r) * 256 + colbase + nt * 16] = acc[mt][nt][r];
}

// ---------- KP: P = cf_it@W1 + b_ne, Q = cf_it@W2. 256 blocks x 1024 thr ----------
__global__ __launch_bounds__(1024) void kp(
    const float* __restrict__ cf, const float* __restrict__ Wne_it, const float* __restrict__ bne_it,
    float* __restrict__ P, float* __restrict__ Q) {
  __shared__ float c[256];
  __shared__ float redP[1024];
  __shared__ float redQ[1024];
  int tid = threadIdx.x;
  int r = blockIdx.x >> 1, half = blockIdx.x & 1;
  if (tid < 256) c[tid] = cf[r * 256 + tid];
  __syncthreads();
  int cc = tid & 127, s = tid >> 7;
  int col = half * 128 + cc;
  int k0 = s * 32;
  float accP = 0.f, accQ = 0.f;
  #pragma unroll 8
  for (int kk = 0; kk < 32; ++kk) {
    float cv = c[k0 + kk];
    accP += cv * Wne_it[(k0 + kk) * 256 + col];
    accQ += cv * Wne_it[(256 + k0 + kk) * 256 + col];
  }
  redP[tid] = accP;
  redQ[tid] = accQ;
  __syncthreads();
  if (tid < 128) {
    float pv = bne_it[half * 128 + tid], qv = 0.f;
    #pragma unroll
    for (int q = 0; q < 8; ++q) { pv += redP[q * 128 + tid]; qv += redQ[q * 128 + tid]; }
    P[r * 256 + half * 128 + tid] = pv;
    Q[r * 256 + half * 128 + tid] = qv;
  }
}

// ---------- K4b: cf_next[i] = max over masked (j,t) of msg. 256 blocks x 1024 thr ----------
__global__ __launch_bounds__(1024) void k4b_scatter(
    const float* __restrict__ P, const float* __restrict__ Q, const float* __restrict__ R,
    const float* __restrict__ elog, const float* __restrict__ ex0,
    const float* __restrict__ Wne_it, float* __restrict__ cfn) {
  __shared__ float sl[512];
  __shared__ float se[128];
  __shared__ float red[1024];
  int tid = threadIdx.x;
  int i = blockIdx.x >> 1, half = blockIdx.x & 1;
  if (ex0[i] == 0.f) {                       // block-uniform branch, before any sync
    if (tid < 128) cfn[i * 256 + half * 128 + tid] = 0.f;
    return;
  }
  if (tid < 512) sl[tid] = elog[i * 512 + tid];
  if (tid < 128) se[tid] = ex0[tid];
  __syncthreads();
  int cc = tid & 127, s = tid >> 7;          // 8 j-slices of 16
  int col = half * 128 + cc;
  float p = P[i * 256 + col];
  float w40 = Wne_it[768 * 256 + col];
  float w41 = Wne_it[769 * 256 + col];
  float w42 = Wne_it[770 * 256 + col];
  float w43 = Wne_it[771 * 256 + col];
  float acc = 0.f;                           // zero-init == relu + empty case
  for (int j = s * 16; j < s * 16 + 16; ++j) {
    if (se[j] == 0.f) continue;              // wave-uniform
    float base = p + Q[j * 256 + col] + R[(size_t)(i * 128 + j) * 256 + col];
    float l0 = sl[j * 4 + 0], l1 = sl[j * 4 + 1], l2 = sl[j * 4 + 2], l3 = sl[j * 4 + 3];
    if (l0 > 0.f) { float m = base + l0 * w40; acc = acc > m ? acc : m; }
    if (l1 > 0.f) { float m = base + l1 * w41; acc = acc > m ? acc : m; }
    if (l2 > 0.f) { float m = base + l2 * w42; acc = acc > m ? acc : m; }
    if (l3 > 0.f) { float m = base + l3 * w43; acc = acc > m ? acc : m; }
  }
  red[tid] = acc;
  __syncthreads();
  if (tid < 128) {
    float m = red[tid];
    #pragma unroll
    for (int q = 1; q < 8; ++q) { float v = red[q * 128 + tid]; m = m > v ? m : v; }
    cfn[i * 256 + half * 128 + tid] = m;
  }
}

// ---------- K6a: h = relu([cf0|cf1|cf2]@W_child + bc). 256 blocks x 1024 thr ----------
__global__ __launch_bounds__(1024) void k6a(
    const float* __restrict__ cf0, const float* __restrict__ cf1, const float* __restrict__ cf2,
    const float* __restrict__ Wc, const float* __restrict__ bc, float* __restrict__ h) {
  __shared__ float af[768];
  __shared__ float red[1024];
  int tid = threadIdx.x;
  int m = blockIdx.x >> 1, half = blockIdx.x & 1;
  if (tid < 768) {
    float v = tid < 256 ? cf0[m * 256 + tid]
            : tid < 512 ? cf1[m * 256 + tid - 256]
                        : cf2[m * 256 + tid - 512];
    af[tid] = v;
  }
  __syncthreads();
  int cc = tid & 127, s = tid >> 7;          // 8 k-slices of 96
  int col = half * 128 + cc;
  int k0 = s * 96;
  float acc = 0.f;
  #pragma unroll 8
  for (int kk = 0; kk < 96; ++kk)
    acc += af[k0 + kk] * Wc[(k0 + kk) * 256 + col];
  red[tid] = acc;
  __syncthreads();
  if (tid < 128) {
    float v = bc[half * 128 + tid];
    #pragma unroll
    for (int q = 0; q < 8; ++q) v += red[q * 128 + tid];
    h[m * 256 + half * 128 + tid] = v > 0.f ? v : 0.f;
  }
}

// ---------- K6b: out_co = relu(h@W2+b2); sem = h@Wsem+bsem. 256 blocks x 1024 thr ----------
__global__ __launch_bounds__(1024) void k6b(
    const float* __restrict__ h, const float* __restrict__ W2, const float* __restrict__ b2,
    const float* __restrict__ Wsem, const float* __restrict__ bsem, float* __restrict__ out) {
  __shared__ float hb[256];
  __shared__ float red[1024];
  __shared__ float redS[8 * 57];
  int tid = threadIdx.x;
  int m = blockIdx.x >> 1, half = blockIdx.x & 1;
  if (tid < 256) hb[tid] = h[m * 256 + tid];
  __syncthreads();
  int cc = tid & 127, s = tid >> 7;          // 8 k-slices of 32
  int col = half * 128 + cc;
  int k0 = s * 32;
  float acc = 0.f;
  #pragma unroll 8
  for (int kk = 0; kk < 32; ++kk)
    acc += hb[k0 + kk] * W2[(k0 + kk) * 256 + col];
  red[tid] = acc;
  float accs = 0.f;
  if (half == 0 && cc < 57) {
    #pragma unroll 8
    for (int kk = 0; kk < 32; ++kk)
      accs += hb[k0 + kk] * Wsem[(k0 + kk) * 57 + cc];
    redS[s * 57 + cc] = accs;
  }
  __syncthreads();
  if (tid < 128) {
    float v = b2[half * 128 + tid];
    #pragma unroll
    for (int q = 0; q < 8; ++q) v += red[q * 128 + tid];
    out[m * 256 + half * 128 + tid] = v > 0.f ? v : 0.f;
  }
  if (half == 0 && tid < 57) {
    float v = bsem[tid];
    #pragma unroll
    for (int q = 0; q < 8; ++q) v += redS[q * 57 + tid];
    out[32768 + m * 57 + tid] = v;
  }
}

extern "C" void kernel_launch(void* const* d_in, const int* in_sizes, int n_in,
                              void* d_out, int out_size, void* d_ws, size_t ws_size,
                              hipStream_t stream) {
  const float* p0  = (const float*)d_in[0];
  const float* p1  = (const float*)d_in[1];
  const float* p2  = (const float*)d_in[2];
  const float* Wp  = (const float*)d_in[3];
  const float* bp  = (const float*)d_in[4];
  const float* Wex = (const float*)d_in[5];
  const float* bex = (const float*)d_in[6];
  const float* Wsm = (const float*)d_in[7];
  const float* bsm = (const float*)d_in[8];
  const float* Wel = (const float*)d_in[9];
  const float* bel = (const float*)d_in[10];
  const float* Wee = (const float*)d_in[11];
  const float* bee = (const float*)d_in[12];
  const float* Wne = (const float*)d_in[13];
  const float* bne = (const float*)d_in[14];
  const float* Wc  = (const float*)d_in[15];
  const float* bc  = (const float*)d_in[16];
  const float* W2  = (const float*)d_in[17];
  const float* b2  = (const float*)d_in[18];
  float* out = (float*)d_out;

  char* ws = (char*)d_ws;
  float*    cf0  = (float*)(ws + 0);
  float*    cf1  = (float*)(ws + 131072);
  float*    cf2  = (float*)(ws + 262144);
  float*    Ab   = (float*)(ws + 393216);
  float*    Bb   = (float*)(ws + 524288);
  float*    Pb   = (float*)(ws + 655360);
  float*    Qb   = (float*)(ws + 786432);
  float*    hws  = (float*)(ws + 917504);     // 128K
  float*    ex0  = (float*)(ws + 1048576);
  ushort_t* W3T  = (ushort_t*)(ws + 1179648); // 256K
  ushort_t* ELbf = (ushort_t*)(ws + 2097152); // 8M
  float*    R    = (float*)(ws + 12582912);   // 16M

  float* out_ex  = out + 40064;     // [128]
  float* out_el  = out + 40192;     // [128,128,4]

  k1_parent<<<512, 256, 0, stream>>>(p0, p1, p2, Wp, bp, cf0);
  k2_ab<<<256, 1024, 0, stream>>>(cf0, Wel, Wex, bex, Ab, Bb, ex0, out_ex);
  k2b_pack<<<512, 256, 0, stream>>>(Wne, W3T);
  k3_edge<<<16384, 256, 0, stream>>>(Ab, Bb, bel, Wee, bee, ELbf, out_el);
  for (int it = 0; it < 2; ++it) {
    const float* Wne_it = Wne + (size_t)it * 772 * 256;
    const float* cfi = it ? cf1 : cf0;
    float* cfn = it ? cf2 : cf1;
    k_gemm<<<dim3(128, 2), 256, 0, stream>>>(ELbf, W3T + it * 65536, R);
    kp<<<256, 1024, 0, stream>>>(cfi, Wne_it, bne + it * 256, Pb, Qb);
    k4b_scatter<<<256, 1024, 0, stream>>>(Pb, Qb, R, out_el, ex0, Wne_it, cfn);
  }
  k6a<<<256, 1024, 0, stream>>>(cf0, cf1, cf2, Wc, bc, hws);
  k6b<<<256, 1024, 0, stream>>>(hws, W2, b2, Wsm, bsm, out);
}